// Round 4
// baseline (814.843 us; speedup 1.0000x reference)
//
#include <hip/hip_runtime.h>

typedef __attribute__((ext_vector_type(8))) short short8;
typedef __attribute__((ext_vector_type(4))) float f4;

__device__ __forceinline__ float b2f(unsigned short u) {
  union { unsigned int i; float f; } v; v.i = ((unsigned int)u) << 16; return v.f;
}
__device__ __forceinline__ unsigned short f2b(float f) {
  union { float f; unsigned int i; } v; v.f = f;
  unsigned int r = (v.i + 0x7FFFu + ((v.i >> 16) & 1u)) >> 16;
  return (unsigned short)r;
}
// HW packed f32->bf16 (RNE), 1 instr for 2 values: lo16 = bf16(a), hi16 = bf16(b)
__device__ __forceinline__ unsigned int cvt2(float a, float b) {
  unsigned int r;
  asm("v_cvt_pk_bf16_f32 %0, %1, %2" : "=v"(r) : "v"(a), "v"(b));
  return r;
}
// native 2^x
__device__ __forceinline__ float exp2v(float x) {
  float r;
  asm("v_exp_f32 %0, %1" : "=v"(r) : "v"(x));
  return r;
}

// WF32=true: p is float*, convert on load. WF32=false: p is bf16 bits (unsigned short*).
template<bool WF32>
__device__ __forceinline__ float ldv(const void* p, int i) {
  if constexpr (WF32) return ((const float*)p)[i];
  else return b2f(((const unsigned short*)p)[i]);
}

template<bool WF32>
__device__ __forceinline__ short8 ld8(const void* p, long idx) {
  if constexpr (WF32) {
    const float4* f = (const float4*)((const float*)p + idx);
    float4 a = f[0], b = f[1];
    union { unsigned int u[4]; short8 s; } r;
    r.u[0] = cvt2(a.x, a.y);
    r.u[1] = cvt2(a.z, a.w);
    r.u[2] = cvt2(b.x, b.y);
    r.u[3] = cvt2(b.z, b.w);
    return r.s;
  } else {
    return *(const short8*)((const unsigned short*)p + idx);
  }
}

// ---- one-shot weight f32->bf16 conversion into ws ----
#define OFF_PROJW 196608
#define OFF_QB    262144
#define OFF_VB    262400
#define OFF_PB    262656
#define OFF_LSC   262912
#define CONV_TOT  262920

__global__ void conv_kernel(const float* __restrict__ qkv_w, const float* __restrict__ proj_w,
                            const float* __restrict__ q_bias, const float* __restrict__ v_bias,
                            const float* __restrict__ proj_b, const float* __restrict__ lsc,
                            unsigned short* __restrict__ wbf) {
  int i = blockIdx.x * 256 + threadIdx.x;
  if (i >= CONV_TOT) return;
  float v;
  if (i < OFF_PROJW)      v = qkv_w[i];
  else if (i < OFF_QB)    v = proj_w[i - OFF_PROJW];
  else if (i < OFF_VB)    v = q_bias[i - OFF_QB];
  else if (i < OFF_PB)    v = v_bias[i - OFF_VB];
  else if (i < OFF_LSC)   v = proj_b[i - OFF_PB];
  else                    v = lsc[i - OFF_LSC];
  wbf[i] = f2b(v);
}

// ---- CPB MLP -> biasv[h][d] = 16*sigmoid(table[d][h]) * log2(e), d in [0,127) ----
// (pre-scaled by log2(e) so the softmax runs in base-2 units)
__global__ void cpb_kernel(const float* __restrict__ w1, const float* __restrict__ b1,
                           const float* __restrict__ w2, float* __restrict__ biasv) {
  int p = blockIdx.x * 256 + threadIdx.x;
  if (p >= 127 * 8) return;
  int d = p >> 3, h = p & 7;
  float t = (float)(d - 63) * (8.0f / 63.0f);
  float sgn = (float)((t > 0.f) - (t < 0.f));
  float rc = sgn * log2f(fabsf(t) + 1.f) * (1.f / 3.f);
  float acc = 0.f;
  for (int j = 0; j < 512; ++j) {
    float hj = fmaxf(rc * w1[j] + b1[j], 0.f);
    acc += hj * w2[h * 512 + j];
  }
  biasv[h * 128 + d] = (16.f / (1.f + __expf(-acc))) * 1.442695040889f;
}

// LDS strides (bf16 elems), 16B-aligned rows, <=2-way bank aliasing
#define XS_S 264
#define QN_S 40
#define VT_S 72
#define PS_S 72

// R3 structure (traffic-verified: FETCH ~148MB, WRITE ~264MB), VALU-thinned:
//  - all f32->bf16 via v_cvt_pk_bf16_f32 (bit-compatible RNE, ~1/8 the VALU ops)
//  - vt writeback packed as ds_write_b64
//  - base-2 softmax (bias pre-scaled by log2e, native v_exp_f32)
//  - P stored unnormalized; 1/sum applied to o after PV
//  - s_setprio(1) around MFMA clusters (2 async blocks/CU -> role diversity)
// LDS: xs 33792 + qn 5120 + kn 5120 + vt 4608 + Ps 9216 + bvs 4096 = 61952 B
//   -> 2 blocks/CU at 256 threads. Barriers: 17 per block.
template<bool WF32>
__launch_bounds__(256, 2)
__global__ void wattn_kernel(const float* __restrict__ x, const void* __restrict__ qkv_w,
                             const void* __restrict__ q_bias, const void* __restrict__ v_bias,
                             const void* __restrict__ lsc, const float* __restrict__ biasv,
                             const void* __restrict__ proj_w, const void* __restrict__ proj_b,
                             float* __restrict__ out) {
  __shared__ __align__(16) unsigned short xs[64 * XS_S];
  __shared__ __align__(16) unsigned short qn[64 * QN_S];
  __shared__ __align__(16) unsigned short kn[64 * QN_S];
  __shared__ __align__(16) unsigned short vt[32 * VT_S];
  __shared__ __align__(16) unsigned short Ps[64 * PS_S];  // cols 0..31 double as Oh
  __shared__ float bvs[8 * 128];

  const int tid = threadIdx.x;
  const int lane = tid & 63;
  const int wv = tid >> 6;
  const int c = lane & 15;
  const int quad = lane >> 4;

  const long b = blockIdx.x;
  const long xbase = b * (64L * 256L);

  // stage x window into LDS as bf16, coalesced float4 loads
#pragma unroll
  for (int i = 0; i < 8; ++i) {
    int chunk = tid + 256 * i;
    int row = chunk >> 5;
    int col = (chunk & 31) * 8;
    *(short8*)&xs[row * XS_S + col] = ld8<true>(x, xbase + row * 256 + col);
  }
  for (int i = tid; i < 1024; i += 256) bvs[i] = biasv[i];

  // proj accumulator: only waves 2/3 (each owns 128 output cols)
  f4 accp[4][8];
  if (wv >= 2) {
#pragma unroll
    for (int i = 0; i < 4; ++i)
#pragma unroll
      for (int j = 0; j < 8; ++j) accp[i][j] = (f4){0.f, 0.f, 0.f, 0.f};
  }

  __syncthreads();

  for (int h = 0; h < 8; ++h) {
    // ===== phase A: QKV(h) + proj(h-1) =====
    if (wv < 2) {
      // wv0 -> q, wv1 -> k: 64 rows x 32 cols
      f4 acc[4][2];
#pragma unroll
      for (int mt = 0; mt < 4; ++mt)
#pragma unroll
        for (int t = 0; t < 2; ++t) acc[mt][t] = (f4){0.f, 0.f, 0.f, 0.f};

      const long wbase = (long)(wv * 256 + h * 32) * 256L;
      __builtin_amdgcn_s_setprio(1);
#pragma unroll
      for (int k0 = 0; k0 < 256; k0 += 32) {
        short8 a[4], bb[2];
#pragma unroll
        for (int mt = 0; mt < 4; ++mt)
          a[mt] = *(const short8*)&xs[(16 * mt + c) * XS_S + k0 + quad * 8];
#pragma unroll
        for (int t = 0; t < 2; ++t)
          bb[t] = ld8<WF32>(qkv_w, wbase + (long)(16 * t + c) * 256 + k0 + quad * 8);
#pragma unroll
        for (int mt = 0; mt < 4; ++mt)
#pragma unroll
          for (int t = 0; t < 2; ++t)
            acc[mt][t] = __builtin_amdgcn_mfma_f32_16x16x32_bf16(a[mt], bb[t], acc[mt][t], 0, 0, 0);
      }
      __builtin_amdgcn_s_setprio(0);

      if (wv == 0) {
        float qb0 = ldv<WF32>(q_bias, h * 32 + c);
        float qb1 = ldv<WF32>(q_bias, h * 32 + 16 + c);
#pragma unroll
        for (int mt = 0; mt < 4; ++mt)
#pragma unroll
          for (int r = 0; r < 4; ++r) {
            float v0 = acc[mt][0][r] + qb0;
            float v1 = acc[mt][1][r] + qb1;
            float ss = v0 * v0 + v1 * v1;
            ss += __shfl_xor(ss, 1);
            ss += __shfl_xor(ss, 2);
            ss += __shfl_xor(ss, 4);
            ss += __shfl_xor(ss, 8);
            float ri = rsqrtf(ss);
            unsigned int u = cvt2(v0 * ri, v1 * ri);
            int m = 16 * mt + quad * 4 + r;
            qn[m * QN_S + c] = (unsigned short)u;
            qn[m * QN_S + 16 + c] = (unsigned short)(u >> 16);
          }
      } else {
#pragma unroll
        for (int mt = 0; mt < 4; ++mt)
#pragma unroll
          for (int r = 0; r < 4; ++r) {
            float v0 = acc[mt][0][r];
            float v1 = acc[mt][1][r];
            float ss = v0 * v0 + v1 * v1;
            ss += __shfl_xor(ss, 1);
            ss += __shfl_xor(ss, 2);
            ss += __shfl_xor(ss, 4);
            ss += __shfl_xor(ss, 8);
            float ri = rsqrtf(ss);
            unsigned int u = cvt2(v0 * ri, v1 * ri);
            int m = 16 * mt + quad * 4 + r;
            kn[m * QN_S + c] = (unsigned short)u;
            kn[m * QN_S + 16 + c] = (unsigned short)(u >> 16);
          }
      }
    } else {
      // wv2/wv3: v half (64 rows x 16 cols) + proj(h-1) half (64 rows x 128 cols, K=32)
      const int half = wv & 1;
      f4 acc[4];
#pragma unroll
      for (int mt = 0; mt < 4; ++mt) acc[mt] = (f4){0.f, 0.f, 0.f, 0.f};

      const long wbase = (long)(512 + h * 32 + 16 * half + c) * 256L;
      __builtin_amdgcn_s_setprio(1);
#pragma unroll
      for (int k0 = 0; k0 < 256; k0 += 32) {
        short8 bb = ld8<WF32>(qkv_w, wbase + k0 + quad * 8);
#pragma unroll
        for (int mt = 0; mt < 4; ++mt) {
          short8 a = *(const short8*)&xs[(16 * mt + c) * XS_S + k0 + quad * 8];
          acc[mt] = __builtin_amdgcn_mfma_f32_16x16x32_bf16(a, bb, acc[mt], 0, 0, 0);
        }
      }
      __builtin_amdgcn_s_setprio(0);

      float vb = ldv<WF32>(v_bias, h * 32 + 16 * half + c);
      // 4 consecutive m per mt -> pack to one b64 store (addr 8B-aligned)
#pragma unroll
      for (int mt = 0; mt < 4; ++mt) {
        uint2 pk;
        pk.x = cvt2(acc[mt][0] + vb, acc[mt][1] + vb);
        pk.y = cvt2(acc[mt][2] + vb, acc[mt][3] + vb);
        int m0 = 16 * mt + quad * 4;
        *(uint2*)&vt[(16 * half + c) * VT_S + m0] = pk;
      }

      if (h > 0) {
        const int hp = h - 1;
        short8 ao[4];
#pragma unroll
        for (int mt = 0; mt < 4; ++mt)
          ao[mt] = *(const short8*)&Ps[(16 * mt + c) * PS_S + quad * 8];
        __builtin_amdgcn_s_setprio(1);
#pragma unroll
        for (int nt = 0; nt < 8; ++nt) {
          short8 bp = ld8<WF32>(proj_w,
              (long)(128 * half + 16 * nt + c) * 256L + hp * 32 + quad * 8);
#pragma unroll
          for (int mt = 0; mt < 4; ++mt)
            accp[mt][nt] = __builtin_amdgcn_mfma_f32_16x16x32_bf16(ao[mt], bp, accp[mt][nt], 0, 0, 0);
        }
        __builtin_amdgcn_s_setprio(0);
      }
    }
    __syncthreads();  // qn/kn/vt ready; Oh(h-1) consumed

    // ===== phase B: attention (each wave owns 16-row strip), base-2 softmax =====
    {
      float scale2 = __expf(fminf(ldv<WF32>(lsc, h), 4.6051702f)) * 1.442695040889f;

      f4 s[4];
#pragma unroll
      for (int nt = 0; nt < 4; ++nt) s[nt] = (f4){0.f, 0.f, 0.f, 0.f};
      short8 aq = *(const short8*)&qn[(16 * wv + c) * QN_S + quad * 8];
      __builtin_amdgcn_s_setprio(1);
#pragma unroll
      for (int nt = 0; nt < 4; ++nt) {
        short8 bk = *(const short8*)&kn[(16 * nt + c) * QN_S + quad * 8];
        s[nt] = __builtin_amdgcn_mfma_f32_16x16x32_bf16(aq, bk, s[nt], 0, 0, 0);
      }
      __builtin_amdgcn_s_setprio(0);

      const float* bvh = bvs + h * 128 + 63;
      float inv[4];
#pragma unroll
      for (int r = 0; r < 4; ++r) {
        int m = 16 * wv + quad * 4 + r;
        float l[4];
#pragma unroll
        for (int nt = 0; nt < 4; ++nt)
          l[nt] = s[nt][r] * scale2 + bvh[m - 16 * nt - c];
        float mx = fmaxf(fmaxf(l[0], l[1]), fmaxf(l[2], l[3]));
        mx = fmaxf(mx, __shfl_xor(mx, 1));
        mx = fmaxf(mx, __shfl_xor(mx, 2));
        mx = fmaxf(mx, __shfl_xor(mx, 4));
        mx = fmaxf(mx, __shfl_xor(mx, 8));
        float p[4];
#pragma unroll
        for (int nt = 0; nt < 4; ++nt) p[nt] = exp2v(l[nt] - mx);
        // store unnormalized P immediately (PV doesn't wait on the sum-reduce)
        unsigned int u01 = cvt2(p[0], p[1]);
        unsigned int u23 = cvt2(p[2], p[3]);
        Ps[m * PS_S + c]      = (unsigned short)u01;
        Ps[m * PS_S + 16 + c] = (unsigned short)(u01 >> 16);
        Ps[m * PS_S + 32 + c] = (unsigned short)u23;
        Ps[m * PS_S + 48 + c] = (unsigned short)(u23 >> 16);
        float sum = p[0] + p[1] + p[2] + p[3];
        sum += __shfl_xor(sum, 1);
        sum += __shfl_xor(sum, 2);
        sum += __shfl_xor(sum, 4);
        sum += __shfl_xor(sum, 8);
        inv[r] = 1.f / sum;
      }

      // PV (intra-wave LDS dep on wave-private Ps rows)
      f4 o[2];
      o[0] = (f4){0.f, 0.f, 0.f, 0.f};
      o[1] = (f4){0.f, 0.f, 0.f, 0.f};
      __builtin_amdgcn_s_setprio(1);
#pragma unroll
      for (int k0 = 0; k0 < 64; k0 += 32) {
        short8 ap = *(const short8*)&Ps[(16 * wv + c) * PS_S + k0 + quad * 8];
#pragma unroll
        for (int t = 0; t < 2; ++t) {
          short8 bvv = *(const short8*)&vt[(16 * t + c) * VT_S + k0 + quad * 8];
          o[t] = __builtin_amdgcn_mfma_f32_16x16x32_bf16(ap, bvv, o[t], 0, 0, 0);
        }
      }
      __builtin_amdgcn_s_setprio(0);
      // Oh write into this wave's own Ps rows, cols 0..31 (reads above precede
      // in program order; rows are wave-disjoint). Apply deferred 1/sum here.
#pragma unroll
      for (int t = 0; t < 2; ++t) {
        unsigned int u01 = cvt2(o[t][0] * inv[0], o[t][1] * inv[1]);
        unsigned int u23 = cvt2(o[t][2] * inv[2], o[t][3] * inv[3]);
        int m0 = 16 * wv + quad * 4;
        Ps[(m0 + 0) * PS_S + 16 * t + c] = (unsigned short)u01;
        Ps[(m0 + 1) * PS_S + 16 * t + c] = (unsigned short)(u01 >> 16);
        Ps[(m0 + 2) * PS_S + 16 * t + c] = (unsigned short)u23;
        Ps[(m0 + 3) * PS_S + 16 * t + c] = (unsigned short)(u23 >> 16);
      }
    }
    __syncthreads();  // Oh(h) ready for next phase A's proj
  }

  // ===== final proj (h=7) + epilogue on waves 2/3 =====
  if (wv >= 2) {
    const int half = wv & 1;
    short8 ao[4];
#pragma unroll
    for (int mt = 0; mt < 4; ++mt)
      ao[mt] = *(const short8*)&Ps[(16 * mt + c) * PS_S + quad * 8];
#pragma unroll
    for (int nt = 0; nt < 8; ++nt) {
      short8 bp = ld8<WF32>(proj_w,
          (long)(128 * half + 16 * nt + c) * 256L + 7 * 32 + quad * 8);
#pragma unroll
      for (int mt = 0; mt < 4; ++mt)
        accp[mt][nt] = __builtin_amdgcn_mfma_f32_16x16x32_bf16(ao[mt], bp, accp[mt][nt], 0, 0, 0);
    }

    float pb[8];
#pragma unroll
    for (int nt = 0; nt < 8; ++nt) pb[nt] = ldv<WF32>(proj_b, 128 * half + 16 * nt + c);
    float* og = out + b * 16384L;
#pragma unroll
    for (int mt = 0; mt < 4; ++mt)
#pragma unroll
      for (int r = 0; r < 4; ++r) {
        int m = 16 * mt + quad * 4 + r;
#pragma unroll
        for (int nt = 0; nt < 8; ++nt)
          og[m * 256 + 128 * half + 16 * nt + c] = accp[mt][nt][r] + pb[nt];
      }
  }
}

extern "C" void kernel_launch(void* const* d_in, const int* in_sizes, int n_in,
                              void* d_out, int out_size, void* d_ws, size_t ws_size,
                              hipStream_t stream) {
  const float* x      = (const float*)d_in[0];
  const float* qkv_w  = (const float*)d_in[1];
  const float* q_bias = (const float*)d_in[2];
  const float* v_bias = (const float*)d_in[3];
  const float* lsc    = (const float*)d_in[4];
  const float* cpb_w1 = (const float*)d_in[5];
  const float* cpb_b1 = (const float*)d_in[6];
  const float* cpb_w2 = (const float*)d_in[7];
  const float* proj_w = (const float*)d_in[8];
  const float* proj_b = (const float*)d_in[9];
  float* out = (float*)d_out;

  float* biasv = (float*)d_ws;                                 // 1024 f32 @ 0
  unsigned short* wbf = (unsigned short*)((char*)d_ws + 4096); // bf16 weights

  int nwin = in_sizes[0] / (64 * 256);
  size_t need = 4096 + (size_t)CONV_TOT * 2 + 64;

  cpb_kernel<<<4, 256, 0, stream>>>(cpb_w1, cpb_b1, cpb_w2, biasv);

  if (ws_size >= need) {
    conv_kernel<<<(CONV_TOT + 255) / 256, 256, 0, stream>>>(
        qkv_w, proj_w, q_bias, v_bias, proj_b, lsc, wbf);
    wattn_kernel<false><<<nwin, 256, 0, stream>>>(
        x, wbf, wbf + OFF_QB, wbf + OFF_VB, wbf + OFF_LSC, biasv,
        wbf + OFF_PROJW, wbf + OFF_PB, out);
  } else {
    wattn_kernel<true><<<nwin, 256, 0, stream>>>(
        x, qkv_w, q_bias, v_bias, lsc, biasv, proj_w, proj_b, out);
  }
}